// Round 1
// baseline (1131.738 us; speedup 1.0000x reference)
//
#include <hip/hip_runtime.h>

#define N_NODES 100000
#define N_EDGES 3200000
#define N_FEAT 24
#define M_CNT (N_NODES + 1)

// ---------------- CSR build ----------------

__global__ void zero_kernel(int* __restrict__ p, int n) {
    int i = blockIdx.x * blockDim.x + threadIdx.x;
    if (i < n) p[i] = 0;
}

__global__ void hist_kernel(const int* __restrict__ row, int* __restrict__ counts, int e) {
    int stride = gridDim.x * blockDim.x;
    for (int i = blockIdx.x * blockDim.x + threadIdx.x; i < e; i += stride)
        atomicAdd(&counts[row[i]], 1);
}

// Single-block exclusive scan: starts[i] = sum_{j<i} counts[j], for i in [0, m)
__global__ __launch_bounds__(1024) void scan_kernel(const int* __restrict__ counts,
                                                    int* __restrict__ starts, int m) {
    __shared__ int part[1024];
    const int tid = threadIdx.x;
    const int chunk = (m + 1023) >> 10;
    int lo = tid * chunk;
    int hi = min(m, lo + chunk);
    int s = 0;
    for (int j = lo; j < hi; ++j) s += counts[j];
    part[tid] = s;
    __syncthreads();
    // Hillis-Steele inclusive scan over 1024 partials
    for (int off = 1; off < 1024; off <<= 1) {
        int v = (tid >= off) ? part[tid - off] : 0;
        __syncthreads();
        part[tid] += v;
        __syncthreads();
    }
    int run = (tid > 0) ? part[tid - 1] : 0;
    for (int j = lo; j < hi; ++j) {
        starts[j] = run;
        run += counts[j];
    }
}

__global__ void copy_kernel(const int* __restrict__ a, int* __restrict__ b, int n) {
    int i = blockIdx.x * blockDim.x + threadIdx.x;
    if (i < n) b[i] = a[i];
}

__global__ void scatter_kernel(const int* __restrict__ row, const int* __restrict__ col,
                               const float* __restrict__ val, int* __restrict__ cursor,
                               int* __restrict__ ccol, float* __restrict__ cval, int e) {
    int stride = gridDim.x * blockDim.x;
    for (int i = blockIdx.x * blockDim.x + threadIdx.x; i < e; i += stride) {
        int r = row[i];
        int p = atomicAdd(&cursor[r], 1);
        ccol[p] = col[i];
        cval[p] = val[i];
    }
}

// ---------------- SpMM: out[r][f] = sum_e val[e] * src[col[e]][f] ----------------
// 8 threads per row, 3 features per thread. csr col/val broadcast across the
// 8-lane group; x-row read is 96B contiguous across the group.
__global__ __launch_bounds__(256) void spmm_kernel(const int* __restrict__ starts,
                                                   const int* __restrict__ ccol,
                                                   const float* __restrict__ cval,
                                                   const float* __restrict__ src,
                                                   float* __restrict__ dst) {
    int t = blockIdx.x * blockDim.x + threadIdx.x;
    int rowi = t >> 3;
    if (rowi >= N_NODES) return;
    int sub = t & 7;
    int s = starts[rowi];
    int e = starts[rowi + 1];
    float a0 = 0.f, a1 = 0.f, a2 = 0.f;
    for (int i = s; i < e; ++i) {
        int c = ccol[i];
        float v = cval[i];
        const float* xp = src + c * N_FEAT + sub * 3;
        a0 = fmaf(v, xp[0], a0);
        a1 = fmaf(v, xp[1], a1);
        a2 = fmaf(v, xp[2], a2);
    }
    float* op = dst + rowi * N_FEAT + sub * 3;
    op[0] = a0;
    op[1] = a1;
    op[2] = a2;
}

// ---------------- launch ----------------

extern "C" void kernel_launch(void* const* d_in, const int* in_sizes, int n_in,
                              void* d_out, int out_size, void* d_ws, size_t ws_size,
                              hipStream_t stream) {
    const float* x       = (const float*)d_in[0];
    const float* values  = (const float*)d_in[1];
    const int*   row_idx = (const int*)d_in[2];
    const int*   col_idx = (const int*)d_in[3];
    float* out = (float*)d_out;

    char* ws = (char*)d_ws;
    // workspace layout (36,000,256 bytes total)
    int*   counts = (int*)(ws + 0);            // M_CNT ints (also reused as cursor)
    int*   starts = (int*)(ws + 400128);       // M_CNT ints
    int*   ccol   = (int*)(ws + 800256);       // E ints
    float* cval   = (float*)(ws + 13600256);   // E floats
    float* xbuf   = (float*)(ws + 26400256);   // N*F floats

    const int E = N_EDGES;

    // 1. zero counts
    zero_kernel<<<(M_CNT + 255) / 256, 256, 0, stream>>>(counts, M_CNT);
    // 2. histogram of rows
    hist_kernel<<<2048, 256, 0, stream>>>(row_idx, counts, E);
    // 3. exclusive scan -> starts  (starts[N] == E since counts[N]==0)
    scan_kernel<<<1, 1024, 0, stream>>>(counts, starts, M_CNT);
    // 4. cursor = starts
    copy_kernel<<<(M_CNT + 255) / 256, 256, 0, stream>>>(starts, counts, M_CNT);
    // 5. scatter edges into CSR order
    scatter_kernel<<<2048, 256, 0, stream>>>(row_idx, col_idx, values, counts, ccol, cval, E);

    // 6. six SpMM layers, ping-pong xbuf <-> out (ends in out)
    const int spmm_blocks = (N_NODES * 8 + 255) / 256;
    spmm_kernel<<<spmm_blocks, 256, 0, stream>>>(starts, ccol, cval, x,    xbuf);
    spmm_kernel<<<spmm_blocks, 256, 0, stream>>>(starts, ccol, cval, xbuf, out);
    spmm_kernel<<<spmm_blocks, 256, 0, stream>>>(starts, ccol, cval, out,  xbuf);
    spmm_kernel<<<spmm_blocks, 256, 0, stream>>>(starts, ccol, cval, xbuf, out);
    spmm_kernel<<<spmm_blocks, 256, 0, stream>>>(starts, ccol, cval, out,  xbuf);
    spmm_kernel<<<spmm_blocks, 256, 0, stream>>>(starts, ccol, cval, xbuf, out);
}

// Round 2
// 955.099 us; speedup vs baseline: 1.1849x; 1.1849x over previous
//
#include <hip/hip_runtime.h>

#define N_NODES 100000
#define N_EDGES 3200000
#define N_FEAT 24
#define M_CNT (N_NODES + 1)
#define PADF4 8   // padded row = 8 float4 = 32 floats = 128B (one L2 line)

// ---------------- CSR build ----------------

__global__ void zero_kernel(int* __restrict__ p, int n) {
    int i = blockIdx.x * blockDim.x + threadIdx.x;
    if (i < n) p[i] = 0;
}

__global__ void hist_kernel(const int* __restrict__ row, int* __restrict__ counts, int e) {
    int stride = gridDim.x * blockDim.x;
    for (int i = blockIdx.x * blockDim.x + threadIdx.x; i < e; i += stride)
        atomicAdd(&counts[row[i]], 1);
}

// Single-block exclusive scan: starts[i] = sum_{j<i} counts[j]
__global__ __launch_bounds__(1024) void scan_kernel(const int* __restrict__ counts,
                                                    int* __restrict__ starts, int m) {
    __shared__ int part[1024];
    const int tid = threadIdx.x;
    const int chunk = (m + 1023) >> 10;
    int lo = tid * chunk;
    int hi = min(m, lo + chunk);
    int s = 0;
    for (int j = lo; j < hi; ++j) s += counts[j];
    part[tid] = s;
    __syncthreads();
    for (int off = 1; off < 1024; off <<= 1) {
        int v = (tid >= off) ? part[tid - off] : 0;
        __syncthreads();
        part[tid] += v;
        __syncthreads();
    }
    int run = (tid > 0) ? part[tid - 1] : 0;
    for (int j = lo; j < hi; ++j) {
        starts[j] = run;
        run += counts[j];
    }
}

__global__ void copy_kernel(const int* __restrict__ a, int* __restrict__ b, int n) {
    int i = blockIdx.x * blockDim.x + threadIdx.x;
    if (i < n) b[i] = a[i];
}

// Packed (col, val_bits) scatter: ONE 8B random write per edge instead of two 4B.
__global__ void scatter_kernel(const int* __restrict__ row, const int* __restrict__ col,
                               const float* __restrict__ val, int* __restrict__ cursor,
                               int2* __restrict__ epk, int e) {
    int stride = gridDim.x * blockDim.x;
    for (int i = blockIdx.x * blockDim.x + threadIdx.x; i < e; i += stride) {
        int r = row[i];
        int p = atomicAdd(&cursor[r], 1);
        int2 pk;
        pk.x = col[i];
        pk.y = __float_as_int(val[i]);
        epk[p] = pk;
    }
}

// ---------------- pad-copy: x [N][24] -> A [N][32] (pad cols zeroed) ----------------
__global__ __launch_bounds__(256) void pad_copy_kernel(const float4* __restrict__ x4,
                                                       float4* __restrict__ dst) {
    int t = blockIdx.x * blockDim.x + threadIdx.x;
    int r = t >> 3;
    if (r >= N_NODES) return;
    int sub = t & 7;
    float4 v;
    if (sub < 6) v = x4[r * 6 + sub];
    else         v = make_float4(0.f, 0.f, 0.f, 0.f);
    dst[r * PADF4 + sub] = v;
}

// ---------------- SpMM on padded buffers ----------------
// 8 lanes per row; each lane accumulates one float4. Row gather = exactly one
// 128B line. Edge (col,val) is an 8B broadcast load across the group.
__global__ __launch_bounds__(256) void spmm_pad_kernel(const int* __restrict__ starts,
                                                       const int2* __restrict__ epk,
                                                       const float4* __restrict__ src,
                                                       float4* __restrict__ dst) {
    int t = blockIdx.x * blockDim.x + threadIdx.x;
    int rowi = t >> 3;
    if (rowi >= N_NODES) return;
    int sub = t & 7;
    int s = starts[rowi];
    int e = starts[rowi + 1];
    float4 acc = make_float4(0.f, 0.f, 0.f, 0.f);
    for (int i = s; i < e; ++i) {
        int2 pk = epk[i];
        float v = __int_as_float(pk.y);
        float4 xv = src[pk.x * PADF4 + sub];
        acc.x = fmaf(v, xv.x, acc.x);
        acc.y = fmaf(v, xv.y, acc.y);
        acc.z = fmaf(v, xv.z, acc.z);
        acc.w = fmaf(v, xv.w, acc.w);
    }
    dst[rowi * PADF4 + sub] = acc;
}

// Final layer: padded src -> unpadded d_out [N][24]
__global__ __launch_bounds__(256) void spmm_final_kernel(const int* __restrict__ starts,
                                                         const int2* __restrict__ epk,
                                                         const float4* __restrict__ src,
                                                         float* __restrict__ out) {
    int t = blockIdx.x * blockDim.x + threadIdx.x;
    int rowi = t >> 3;
    if (rowi >= N_NODES) return;
    int sub = t & 7;
    int s = starts[rowi];
    int e = starts[rowi + 1];
    float4 acc = make_float4(0.f, 0.f, 0.f, 0.f);
    for (int i = s; i < e; ++i) {
        int2 pk = epk[i];
        float v = __int_as_float(pk.y);
        float4 xv = src[pk.x * PADF4 + sub];
        acc.x = fmaf(v, xv.x, acc.x);
        acc.y = fmaf(v, xv.y, acc.y);
        acc.z = fmaf(v, xv.z, acc.z);
        acc.w = fmaf(v, xv.w, acc.w);
    }
    if (sub < 6) {
        *(float4*)(out + rowi * N_FEAT + sub * 4) = acc;
    }
}

// ---------------- launch ----------------

extern "C" void kernel_launch(void* const* d_in, const int* in_sizes, int n_in,
                              void* d_out, int out_size, void* d_ws, size_t ws_size,
                              hipStream_t stream) {
    const float* x       = (const float*)d_in[0];
    const float* values  = (const float*)d_in[1];
    const int*   row_idx = (const int*)d_in[2];
    const int*   col_idx = (const int*)d_in[3];
    float* out = (float*)d_out;

    char* ws = (char*)d_ws;
    // workspace layout (52,000,256 bytes total; all offsets 128B-aligned)
    int*    counts = (int*)(ws + 0);            // M_CNT ints (reused as cursor)
    int*    starts = (int*)(ws + 400128);       // M_CNT ints
    int2*   epk    = (int2*)(ws + 800256);      // E packed (col, val) = 25.6 MB
    float4* bufA   = (float4*)(ws + 26400256);  // N*32 floats padded = 12.8 MB
    float4* bufB   = (float4*)(ws + 39200256);  // N*32 floats padded = 12.8 MB

    const int E = N_EDGES;

    zero_kernel<<<(M_CNT + 255) / 256, 256, 0, stream>>>(counts, M_CNT);
    hist_kernel<<<2048, 256, 0, stream>>>(row_idx, counts, E);
    scan_kernel<<<1, 1024, 0, stream>>>(counts, starts, M_CNT);
    copy_kernel<<<(M_CNT + 255) / 256, 256, 0, stream>>>(starts, counts, M_CNT);
    scatter_kernel<<<2048, 256, 0, stream>>>(row_idx, col_idx, values, counts, epk, E);

    const int spmm_blocks = (N_NODES * 8 + 255) / 256;
    pad_copy_kernel<<<spmm_blocks, 256, 0, stream>>>((const float4*)x, bufA);
    spmm_pad_kernel<<<spmm_blocks, 256, 0, stream>>>(starts, epk, bufA, bufB);   // L1
    spmm_pad_kernel<<<spmm_blocks, 256, 0, stream>>>(starts, epk, bufB, bufA);   // L2
    spmm_pad_kernel<<<spmm_blocks, 256, 0, stream>>>(starts, epk, bufA, bufB);   // L3
    spmm_pad_kernel<<<spmm_blocks, 256, 0, stream>>>(starts, epk, bufB, bufA);   // L4
    spmm_pad_kernel<<<spmm_blocks, 256, 0, stream>>>(starts, epk, bufA, bufB);   // L5
    spmm_final_kernel<<<spmm_blocks, 256, 0, stream>>>(starts, epk, bufB, out);  // L6
}

// Round 3
// 573.018 us; speedup vs baseline: 1.9750x; 1.6668x over previous
//
#include <hip/hip_runtime.h>

#define N_NODES 100000
#define N_EDGES 3200000
#define N_FEAT 24
#define PADF4 8                         // padded row = 32 floats = 128B
#define BSHIFT 8                        // 256 rows per bucket
#define NBUCK ((N_NODES + 255) >> 8)    // 391 buckets
#define EPT 16                          // edges per thread in partition
#define TILE (256 * EPT)                // 4096 edges per block-tile
#define NTILES ((N_EDGES + TILE - 1) / TILE)  // 782
#define CAP 12288                       // level-2 LDS staging entries (96KB)

// ---------------- small utils ----------------

__global__ void zero_kernel(int* __restrict__ p, int n) {
    int i = blockIdx.x * blockDim.x + threadIdx.x;
    if (i < n) p[i] = 0;
}

// ---------------- bucket histogram (LDS-aggregated) ----------------
__global__ __launch_bounds__(256) void bhist_kernel(const int* __restrict__ row,
                                                    int* __restrict__ bcnt) {
    __shared__ int h[NBUCK];
    for (int i = threadIdx.x; i < NBUCK; i += 256) h[i] = 0;
    __syncthreads();
    int stride = gridDim.x * blockDim.x;
    for (int i = blockIdx.x * blockDim.x + threadIdx.x; i < N_EDGES; i += stride)
        atomicAdd(&h[row[i] >> BSHIFT], 1);
    __syncthreads();
    for (int i = threadIdx.x; i < NBUCK; i += 256) {
        int c = h[i];
        if (c) atomicAdd(&bcnt[i], c);
    }
}

// ---------------- bucket exclusive scan -> bbase[0..NBUCK], bcursor ----------------
__global__ __launch_bounds__(512) void bscan_kernel(const int* __restrict__ bcnt,
                                                    int* __restrict__ bbase,
                                                    int* __restrict__ bcursor) {
    __shared__ int part[512];
    int tid = threadIdx.x;
    int v = (tid < NBUCK) ? bcnt[tid] : 0;
    part[tid] = v;
    __syncthreads();
    for (int off = 1; off < 512; off <<= 1) {
        int p = (tid >= off) ? part[tid - off] : 0;
        __syncthreads();
        part[tid] += p;
        __syncthreads();
    }
    int ex = (tid > 0) ? part[tid - 1] : 0;
    if (tid <= NBUCK) {
        bbase[tid] = ex;              // bbase[NBUCK] == N_EDGES
        if (tid < NBUCK) bcursor[tid] = ex;
    }
}

// ---------------- level 1: partition edges into bucket regions ----------------
// Per-tile LDS rank + one chunk reservation per (block,bucket): all writes into
// a given line come from one block within one tile -> L2 aggregates full lines.
__global__ __launch_bounds__(256) void part_kernel(const int* __restrict__ row,
                                                   const int* __restrict__ col,
                                                   const float* __restrict__ val,
                                                   int* __restrict__ bcursor,
                                                   int2* __restrict__ epk) {
    __shared__ int h[NBUCK];
    __shared__ int gpos[NBUCK];
    for (int i = threadIdx.x; i < NBUCK; i += 256) h[i] = 0;
    __syncthreads();
    int base = blockIdx.x * TILE + threadIdx.x * EPT;
    int rowj[EPT], rk[EPT];
    #pragma unroll
    for (int j = 0; j < EPT; ++j) {
        int e = base + j;
        if (e < N_EDGES) {
            int r = row[e];
            rowj[j] = r;
            rk[j] = atomicAdd(&h[r >> BSHIFT], 1);
        } else rowj[j] = -1;
    }
    __syncthreads();
    for (int i = threadIdx.x; i < NBUCK; i += 256) {
        int c = h[i];
        gpos[i] = c ? atomicAdd(&bcursor[i], c) : 0;
    }
    __syncthreads();
    #pragma unroll
    for (int j = 0; j < EPT; ++j) {
        if (rowj[j] >= 0) {
            int e = base + j;
            int b = rowj[j] >> BSHIFT;
            int rl = rowj[j] & 255;
            int2 pk;
            pk.x = col[e] | (rl << 17);   // col < 2^17, rl < 2^8
            pk.y = __float_as_int(val[e]);
            epk[gpos[b] + rk[j]] = pk;
        }
    }
}

// ---------------- level 2: exact CSR placement within each bucket ----------------
// One block per bucket. Region (~8K edges) -> LDS staging -> coalesced dump.
// Emits per-row starts[] as a byproduct.
__global__ __launch_bounds__(256) void place_kernel(const int* __restrict__ bbase,
                                                    int2* __restrict__ epk,
                                                    int* __restrict__ starts) {
    __shared__ int rcnt[256];
    __shared__ int rstart[256];
    __shared__ int rcur[256];
    __shared__ int2 stage[CAP];
    int b = blockIdx.x;
    int tid = threadIdx.x;
    int gb = bbase[b];
    int n = bbase[b + 1] - gb;
    rcnt[tid] = 0;
    __syncthreads();
    for (int i = tid; i < n; i += 256) {
        int rl = (epk[gb + i].x >> 17) & 255;
        atomicAdd(&rcnt[rl], 1);
    }
    __syncthreads();
    int v = rcnt[tid];
    rstart[tid] = v;
    __syncthreads();
    for (int off = 1; off < 256; off <<= 1) {
        int p = (tid >= off) ? rstart[tid - off] : 0;
        __syncthreads();
        rstart[tid] += p;
        __syncthreads();
    }
    int ex = rstart[tid] - v;      // exclusive prefix (own read only)
    rstart[tid] = ex;
    rcur[tid] = ex;
    __syncthreads();
    for (int i = tid; i < n; i += 256) {
        int2 p = epk[gb + i];
        int rl = (p.x >> 17) & 255;
        int slot = atomicAdd(&rcur[rl], 1);
        int2 fin;
        fin.x = p.x & 0x1FFFF;
        fin.y = p.y;
        if (slot < CAP) stage[slot] = fin;
        else epk[gb + slot] = fin;   // 45-sigma overflow guard; unreachable
    }
    __syncthreads();
    for (int i = tid; i < n && i < CAP; i += 256) epk[gb + i] = stage[i];
    int r = (b << BSHIFT) + tid;
    if (r < N_NODES) starts[r] = gb + rstart[tid];
    if (b == 0 && tid == 0) starts[N_NODES] = N_EDGES;
}

// ---------------- pad-copy: x [N][24] -> bufA [N][32] ----------------
__global__ __launch_bounds__(256) void pad_copy_kernel(const float4* __restrict__ x4,
                                                       float4* __restrict__ dst) {
    int t = blockIdx.x * blockDim.x + threadIdx.x;
    int r = t >> 3;
    if (r >= N_NODES) return;
    int sub = t & 7;
    float4 v;
    if (sub < 6) v = x4[r * 6 + sub];
    else         v = make_float4(0.f, 0.f, 0.f, 0.f);
    dst[r * PADF4 + sub] = v;
}

// ---------------- SpMM on padded buffers ----------------
__global__ __launch_bounds__(256) void spmm_pad_kernel(const int* __restrict__ starts,
                                                       const int2* __restrict__ epk,
                                                       const float4* __restrict__ src,
                                                       float4* __restrict__ dst) {
    int t = blockIdx.x * blockDim.x + threadIdx.x;
    int rowi = t >> 3;
    if (rowi >= N_NODES) return;
    int sub = t & 7;
    int s = starts[rowi];
    int e = starts[rowi + 1];
    float4 acc = make_float4(0.f, 0.f, 0.f, 0.f);
    for (int i = s; i < e; ++i) {
        int2 pk = epk[i];
        float v = __int_as_float(pk.y);
        float4 xv = src[pk.x * PADF4 + sub];
        acc.x = fmaf(v, xv.x, acc.x);
        acc.y = fmaf(v, xv.y, acc.y);
        acc.z = fmaf(v, xv.z, acc.z);
        acc.w = fmaf(v, xv.w, acc.w);
    }
    dst[rowi * PADF4 + sub] = acc;
}

__global__ __launch_bounds__(256) void spmm_final_kernel(const int* __restrict__ starts,
                                                         const int2* __restrict__ epk,
                                                         const float4* __restrict__ src,
                                                         float* __restrict__ out) {
    int t = blockIdx.x * blockDim.x + threadIdx.x;
    int rowi = t >> 3;
    if (rowi >= N_NODES) return;
    int sub = t & 7;
    int s = starts[rowi];
    int e = starts[rowi + 1];
    float4 acc = make_float4(0.f, 0.f, 0.f, 0.f);
    for (int i = s; i < e; ++i) {
        int2 pk = epk[i];
        float v = __int_as_float(pk.y);
        float4 xv = src[pk.x * PADF4 + sub];
        acc.x = fmaf(v, xv.x, acc.x);
        acc.y = fmaf(v, xv.y, acc.y);
        acc.z = fmaf(v, xv.z, acc.z);
        acc.w = fmaf(v, xv.w, acc.w);
    }
    if (sub < 6) *(float4*)(out + rowi * N_FEAT + sub * 4) = acc;
}

// ---------------- launch ----------------

extern "C" void kernel_launch(void* const* d_in, const int* in_sizes, int n_in,
                              void* d_out, int out_size, void* d_ws, size_t ws_size,
                              hipStream_t stream) {
    const float* x       = (const float*)d_in[0];
    const float* values  = (const float*)d_in[1];
    const int*   row_idx = (const int*)d_in[2];
    const int*   col_idx = (const int*)d_in[3];
    float* out = (float*)d_out;

    char* ws = (char*)d_ws;
    // workspace layout (~51.6MB, 128B-aligned offsets)
    int*    bcnt    = (int*)(ws + 0);          // NBUCK ints
    int*    bbase   = (int*)(ws + 2048);       // NBUCK+1 ints
    int*    bcursor = (int*)(ws + 4096);       // NBUCK ints
    int*    starts  = (int*)(ws + 6144);       // N_NODES+1 ints
    int2*   epk     = (int2*)(ws + 406400);    // E * 8B = 25.6 MB
    float4* bufA    = (float4*)(ws + 26006400);// N*32 floats = 12.8 MB
    float4* bufB    = (float4*)(ws + 38806400);// N*32 floats = 12.8 MB

    zero_kernel<<<2, 256, 0, stream>>>(bcnt, NBUCK);
    bhist_kernel<<<512, 256, 0, stream>>>(row_idx, bcnt);
    bscan_kernel<<<1, 512, 0, stream>>>(bcnt, bbase, bcursor);
    part_kernel<<<NTILES, 256, 0, stream>>>(row_idx, col_idx, values, bcursor, epk);
    place_kernel<<<NBUCK, 256, 0, stream>>>(bbase, epk, starts);

    const int spmm_blocks = (N_NODES * 8 + 255) / 256;
    pad_copy_kernel<<<spmm_blocks, 256, 0, stream>>>((const float4*)x, bufA);
    spmm_pad_kernel<<<spmm_blocks, 256, 0, stream>>>(starts, epk, bufA, bufB);   // L1
    spmm_pad_kernel<<<spmm_blocks, 256, 0, stream>>>(starts, epk, bufB, bufA);   // L2
    spmm_pad_kernel<<<spmm_blocks, 256, 0, stream>>>(starts, epk, bufA, bufB);   // L3
    spmm_pad_kernel<<<spmm_blocks, 256, 0, stream>>>(starts, epk, bufB, bufA);   // L4
    spmm_pad_kernel<<<spmm_blocks, 256, 0, stream>>>(starts, epk, bufA, bufB);   // L5
    spmm_final_kernel<<<spmm_blocks, 256, 0, stream>>>(starts, epk, bufB, out);  // L6
}